// Round 1
// baseline (773.396 us; speedup 1.0000x reference)
//
#include <hip/hip_runtime.h>
#include <hip/hip_bf16.h>

// Triangle attention (starting node), b=1, n=256, d=128, H=4, DH=32.
// Round 0: correct fp32-VALU baseline, 3 kernels, bf16 intermediates in ws.

#define NH  4
#define DHD 32
#define NP  256
#define DD  128

__device__ __forceinline__ float bf2f(ushort u) {
    union { unsigned int v; float f; } c; c.v = ((unsigned int)u) << 16; return c.f;
}
__device__ __forceinline__ ushort f2bf(float f) {
    union { float f; unsigned int v; } c; c.f = f;
    unsigned int x = c.v;
    return (ushort)((x + 0x7FFFu + ((x >> 16) & 1u)) >> 16);  // RNE
}

// ---------------- K1: LayerNorm + qkv/g/bias projections ----------------
// grid 1024 x 256 threads; each wave handles 16 positions (64/block).
__global__ __launch_bounds__(256) void k_lnproj(
    const float* __restrict__ edges, const float* __restrict__ gamma,
    const float* __restrict__ beta,  const float* __restrict__ Wqkv,
    const float* __restrict__ Wb,    const float* __restrict__ Wg,
    const float* __restrict__ bg,
    ushort* __restrict__ Qo, ushort* __restrict__ Ko, ushort* __restrict__ Vo,
    ushort* __restrict__ Go, float* __restrict__ Bo)
{
    __shared__ float xs[4][16][DD];  // 32 KB
    const int tid = threadIdx.x, w = tid >> 6, lane = tid & 63;
    const int p0 = blockIdx.x * 64 + w * 16;
    const float g0 = gamma[lane], g1 = gamma[lane + 64];
    const float be0 = beta[lane], be1 = beta[lane + 64];
    for (int pp = 0; pp < 16; ++pp) {
        const float* ep = edges + (size_t)(p0 + pp) * DD;
        float e0 = ep[lane], e1 = ep[lane + 64];
        float s = e0 + e1;
        #pragma unroll
        for (int off = 1; off < 64; off <<= 1) s += __shfl_xor(s, off);
        float mu = s * (1.0f / 128.0f);
        float d0 = e0 - mu, d1 = e1 - mu;
        float ss = d0 * d0 + d1 * d1;
        #pragma unroll
        for (int off = 1; off < 64; off <<= 1) ss += __shfl_xor(ss, off);
        float rstd = rsqrtf(ss * (1.0f / 128.0f) + 1e-5f);
        xs[w][pp][lane]      = d0 * rstd * g0 + be0;
        xs[w][pp][lane + 64] = d1 * rstd * g1 + be1;
    }
    __syncthreads();
    for (int r = 0; r < 9; ++r) {
        const int c = r * 64 + lane;
        if (c < 516) {
            const float* wcol; int stride;
            if (c < 384)      { wcol = Wqkv + c;       stride = 384; }
            else if (c < 512) { wcol = Wg + (c - 384); stride = 128; }
            else              { wcol = Wb + (c - 512); stride = 4;   }
            float acc[16];
            #pragma unroll
            for (int pp = 0; pp < 16; ++pp) acc[pp] = 0.f;
            for (int e = 0; e < DD; ++e) {
                float wv = wcol[(size_t)e * stride];
                #pragma unroll
                for (int pp = 0; pp < 16; ++pp) acc[pp] += xs[w][pp][e] * wv;
            }
            if (c < 128) {
                #pragma unroll
                for (int pp = 0; pp < 16; ++pp)
                    Qo[(size_t)(p0 + pp) * DD + c] = f2bf(acc[pp]);
            } else if (c < 256) {
                #pragma unroll
                for (int pp = 0; pp < 16; ++pp)
                    Ko[(size_t)(p0 + pp) * DD + (c - 128)] = f2bf(acc[pp]);
            } else if (c < 384) {
                #pragma unroll
                for (int pp = 0; pp < 16; ++pp)
                    Vo[(size_t)(p0 + pp) * DD + (c - 256)] = f2bf(acc[pp]);
            } else if (c < 512) {
                const float bgv = bg[c - 384];
                #pragma unroll
                for (int pp = 0; pp < 16; ++pp) {
                    float gv = 1.0f / (1.0f + __expf(-(acc[pp] + bgv)));
                    Go[(size_t)(p0 + pp) * DD + (c - 384)] = f2bf(gv);
                }
            } else {
                #pragma unroll
                for (int pp = 0; pp < 16; ++pp)
                    Bo[(size_t)(p0 + pp) * 4 + (c - 512)] = acc[pp];
            }
        }
    }
}

// ---------------- K2: attention per (head h, row i) ----------------
// grid 1024 (= 256 i * 4 h) x 256 threads (4 waves).
__global__ __launch_bounds__(256) void k_attn(
    const ushort* __restrict__ Qw, const ushort* __restrict__ Kw,
    const ushort* __restrict__ Vw, const ushort* __restrict__ Gw,
    const float* __restrict__ Bi,  const int* __restrict__ mask,
    ushort* __restrict__ OPre)
{
    __shared__ ushort Kt[DHD][260];   // K^T [e][k], padded: stride 520B -> 2-way max
    __shared__ ushort Vt[DHD][260];   // V^T [d][k]
    __shared__ ushort sm[32][NP];     // attn weights (bf16), one 32-row j-tile
    const int tid = threadIdx.x, w = tid >> 6, lane = tid & 63;
    const int i = blockIdx.x >> 2, h = blockIdx.x & 3;
    const size_t base = ((size_t)i * NP) * DD + (size_t)h * DHD;  // + k*DD + d

    // stage K,V (transposed) into LDS
    for (int pass = 0; pass < 8; ++pass) {
        int idx = pass * 256 + tid;
        int k = idx >> 3, dc = (idx & 7) * 4;
        ushort4 kv = *reinterpret_cast<const ushort4*>(Kw + base + (size_t)k * DD + dc);
        Kt[dc + 0][k] = kv.x; Kt[dc + 1][k] = kv.y;
        Kt[dc + 2][k] = kv.z; Kt[dc + 3][k] = kv.w;
        ushort4 vv = *reinterpret_cast<const ushort4*>(Vw + base + (size_t)k * DD + dc);
        Vt[dc + 0][k] = vv.x; Vt[dc + 1][k] = vv.y;
        Vt[dc + 2][k] = vv.z; Vt[dc + 3][k] = vv.w;
    }
    __syncthreads();

    const float scale = 0.17677669529663687f;   // 32^-0.5
    const float NEGV  = -3.4028234663852886e38f; // float32 lowest

    for (int jt = 0; jt < 8; ++jt) {
        const int j0 = jt * 32;
        // ---- sim + softmax: one query row per wave iteration; lane owns 4 keys
        for (int m = 0; m < 8; ++m) {
            const int jj = w * 8 + m;
            const int j  = j0 + jj;
            float qf[DHD];
            const ushort* qp = Qw + ((size_t)i * NP + j) * DD + (size_t)h * DHD;
            #pragma unroll
            for (int e4 = 0; e4 < 8; ++e4) {
                ushort4 qv = *reinterpret_cast<const ushort4*>(qp + e4 * 4);
                qf[e4 * 4 + 0] = bf2f(qv.x); qf[e4 * 4 + 1] = bf2f(qv.y);
                qf[e4 * 4 + 2] = bf2f(qv.z); qf[e4 * 4 + 3] = bf2f(qv.w);
            }
            const bool masked = (mask[i * NP + j] == 0);
            const int kbase = lane * 4;
            float a0 = 0.f, a1 = 0.f, a2 = 0.f, a3 = 0.f;
            #pragma unroll
            for (int e = 0; e < DHD; ++e) {
                ushort4 kv = *reinterpret_cast<const ushort4*>(&Kt[e][kbase]);
                a0 += qf[e] * bf2f(kv.x); a1 += qf[e] * bf2f(kv.y);
                a2 += qf[e] * bf2f(kv.z); a3 += qf[e] * bf2f(kv.w);
            }
            float attn[4];
            if (masked) {
                // softmax of identical values -> exactly uniform 1/256
                attn[0] = attn[1] = attn[2] = attn[3] = 0.00390625f;
            } else {
                const float* bp = Bi + ((size_t)j * NP + kbase) * 4 + h;
                float sv[4];
                sv[0] = a0 * scale + bp[0];  sv[1] = a1 * scale + bp[4];
                sv[2] = a2 * scale + bp[8];  sv[3] = a3 * scale + bp[12];
                float mx = fmaxf(fmaxf(sv[0], sv[1]), fmaxf(sv[2], sv[3]));
                #pragma unroll
                for (int off = 1; off < 64; off <<= 1) mx = fmaxf(mx, __shfl_xor(mx, off));
                float s0 = 0.f;
                #pragma unroll
                for (int r = 0; r < 4; ++r) { attn[r] = __expf(sv[r] - mx); s0 += attn[r]; }
                #pragma unroll
                for (int off = 1; off < 64; off <<= 1) s0 += __shfl_xor(s0, off);
                float inv = 1.0f / s0;
                attn[0] *= inv; attn[1] *= inv; attn[2] *= inv; attn[3] *= inv;
            }
            ushort4 av;
            av.x = f2bf(attn[0]); av.y = f2bf(attn[1]);
            av.z = f2bf(attn[2]); av.w = f2bf(attn[3]);
            *reinterpret_cast<ushort4*>(&sm[jj][kbase]) = av;
        }
        __syncthreads();
        // ---- PV + gating: thread = (group g -> 4 rows, channel d)
        {
            const int d = tid & 31, g = tid >> 5;
            const int row = g * 4;
            float oo[4] = {0.f, 0.f, 0.f, 0.f};
            for (int k = 0; k < NP; k += 4) {
                ushort4 vv = *reinterpret_cast<const ushort4*>(&Vt[d][k]);
                float v0 = bf2f(vv.x), v1 = bf2f(vv.y), v2 = bf2f(vv.z), v3 = bf2f(vv.w);
                ushort4 w0 = *reinterpret_cast<const ushort4*>(&sm[row + 0][k]);
                ushort4 w1 = *reinterpret_cast<const ushort4*>(&sm[row + 1][k]);
                ushort4 w2 = *reinterpret_cast<const ushort4*>(&sm[row + 2][k]);
                ushort4 w3 = *reinterpret_cast<const ushort4*>(&sm[row + 3][k]);
                oo[0] += bf2f(w0.x) * v0 + bf2f(w0.y) * v1 + bf2f(w0.z) * v2 + bf2f(w0.w) * v3;
                oo[1] += bf2f(w1.x) * v0 + bf2f(w1.y) * v1 + bf2f(w1.z) * v2 + bf2f(w1.w) * v3;
                oo[2] += bf2f(w2.x) * v0 + bf2f(w2.y) * v1 + bf2f(w2.z) * v2 + bf2f(w2.w) * v3;
                oo[3] += bf2f(w3.x) * v0 + bf2f(w3.y) * v1 + bf2f(w3.z) * v2 + bf2f(w3.w) * v3;
            }
            #pragma unroll
            for (int m2 = 0; m2 < 4; ++m2) {
                const int j = j0 + row + m2;
                const size_t off = ((size_t)i * NP + j) * DD + (size_t)h * DHD + d;
                float gv = (mask[i * NP + j] == 0) ? NEGV : bf2f(Gw[off]);
                OPre[off] = f2bf(oo[m2] * gv);
            }
        }
        __syncthreads();
    }
}

// ---------------- K3: output projection + b_out ----------------
__global__ __launch_bounds__(256) void k_outproj(
    const ushort* __restrict__ OPre, const float* __restrict__ Wout,
    const float* __restrict__ bout,  float* __restrict__ out)
{
    __shared__ float xs[4][16][DD];  // 32 KB
    const int tid = threadIdx.x, w = tid >> 6, lane = tid & 63;
    const int p0 = blockIdx.x * 64 + w * 16;
    for (int pp = 0; pp < 16; ++pp) {
        const ushort* src = OPre + (size_t)(p0 + pp) * DD;
        xs[w][pp][lane]      = bf2f(src[lane]);
        xs[w][pp][lane + 64] = bf2f(src[lane + 64]);
    }
    __syncthreads();
    #pragma unroll
    for (int co = 0; co < 2; ++co) {
        const int c = co * 64 + lane;
        float acc[16];
        #pragma unroll
        for (int pp = 0; pp < 16; ++pp) acc[pp] = 0.f;
        for (int e = 0; e < DD; ++e) {
            float wv = Wout[(size_t)e * DD + c];
            #pragma unroll
            for (int pp = 0; pp < 16; ++pp) acc[pp] += xs[w][pp][e] * wv;
        }
        const float bo = bout[c];
        #pragma unroll
        for (int pp = 0; pp < 16; ++pp)
            out[(size_t)(p0 + pp) * DD + c] = acc[pp] + bo;
    }
}

extern "C" void kernel_launch(void* const* d_in, const int* in_sizes, int n_in,
                              void* d_out, int out_size, void* d_ws, size_t ws_size,
                              hipStream_t stream) {
    const float* edges = (const float*)d_in[0];
    const int*   mask  = (const int*)d_in[1];
    const float* gamma = (const float*)d_in[2];
    const float* beta  = (const float*)d_in[3];
    const float* Wqkv  = (const float*)d_in[4];
    const float* Wb    = (const float*)d_in[5];
    const float* Wg    = (const float*)d_in[6];
    const float* bg    = (const float*)d_in[7];
    const float* Wout  = (const float*)d_in[8];
    const float* bout  = (const float*)d_in[9];
    float* out = (float*)d_out;

    char* ws = (char*)d_ws;
    // ws layout (bytes): Q,K,V,G bf16 (16 MiB each), bias f32 (1 MiB), OPre bf16 (16 MiB)
    ushort* Qw  = (ushort*)(ws + 0);
    ushort* Kw  = (ushort*)(ws + 16777216);
    ushort* Vw  = (ushort*)(ws + 33554432);
    ushort* Gw  = (ushort*)(ws + 50331648);
    float*  Bo  = (float*) (ws + 67108864);
    ushort* OPre= (ushort*)(ws + 68157440);
    // total: 84,934,656 bytes

    k_lnproj<<<dim3(1024), dim3(256), 0, stream>>>(edges, gamma, beta, Wqkv, Wb, Wg, bg,
                                                   Qw, Kw, Vw, Gw, Bo);
    k_attn  <<<dim3(1024), dim3(256), 0, stream>>>(Qw, Kw, Vw, Gw, Bo, mask, OPre);
    k_outproj<<<dim3(1024), dim3(256), 0, stream>>>(OPre, Wout, bout, out);
}

// Round 2
// 137.282 us; speedup vs baseline: 5.6336x; 5.6336x over previous
//
#include <hip/hip_runtime.h>
#include <hip/hip_bf16.h>

// Triangle attention (starting node), b=1, n=256, d=128, H=4, DH=32.
// Round 1: all GEMM-shaped phases on bf16 MFMA (16x16x32).

#define NP  256
#define DD  128

typedef short bf16x8 __attribute__((ext_vector_type(8)));
typedef float f32x4  __attribute__((ext_vector_type(4)));

__device__ __forceinline__ float bf2f(ushort u) {
    union { unsigned int v; float f; } c; c.v = ((unsigned int)u) << 16; return c.f;
}
__device__ __forceinline__ ushort f2bf(float f) {
    union { float f; unsigned int v; } c; c.f = f;
    unsigned int x = c.v;
    return (ushort)((x + 0x7FFFu + ((x >> 16) & 1u)) >> 16);  // RNE
}
__device__ __forceinline__ f32x4 mfma16(bf16x8 a, bf16x8 b, f32x4 c) {
    return __builtin_amdgcn_mfma_f32_16x16x32_bf16(a, b, c, 0, 0, 0);
}

#define NEGV (-3.4028234663852886e38f)

// ---------------- K0: W -> bf16, transposed (N-major, K-contiguous) --------
__global__ __launch_bounds__(256) void k_wconv(
    const float* __restrict__ Wqkv, const float* __restrict__ Wg,
    const float* __restrict__ Wout, ushort* __restrict__ WT,
    ushort* __restrict__ WoT)
{
    int idx = blockIdx.x * 256 + threadIdx.x;   // grid 320 -> 81920
    if (idx < 65536) {
        int n = idx >> 7, k = idx & 127;
        float v = (n < 384) ? Wqkv[(size_t)k * 384 + n]
                            : Wg[(size_t)k * 128 + (n - 384)];
        WT[idx] = f2bf(v);
    } else {
        int i2 = idx - 65536;
        int c = i2 >> 7, e = i2 & 127;
        WoT[i2] = f2bf(Wout[(size_t)e * 128 + c]);
    }
}

// ---------------- K1: LayerNorm -> x bf16, + bias GEMV (4 cols) ------------
__global__ __launch_bounds__(256) void k_ln(
    const float* __restrict__ edges, const float* __restrict__ gamma,
    const float* __restrict__ beta,  const float* __restrict__ Wb,
    ushort* __restrict__ Xb, ushort* __restrict__ Bo)
{
    __shared__ float xs[64][132];   // padded: bank = (4r+e)%32 -> 2-way max
    const int tid = threadIdx.x, w = tid >> 6, lane = tid & 63;
    const int p0 = blockIdx.x * 64;
    const float g0 = gamma[lane], g1 = gamma[lane + 64];
    const float b0 = beta[lane],  b1 = beta[lane + 64];
    for (int pp = 0; pp < 16; ++pp) {
        const int row = w * 16 + pp;
        const float* ep = edges + (size_t)(p0 + row) * DD;
        float e0 = ep[lane], e1 = ep[lane + 64];
        float s = e0 + e1;
        #pragma unroll
        for (int off = 1; off < 64; off <<= 1) s += __shfl_xor(s, off);
        float mu = s * 0.0078125f;
        float d0 = e0 - mu, d1 = e1 - mu;
        float ss = d0 * d0 + d1 * d1;
        #pragma unroll
        for (int off = 1; off < 64; off <<= 1) ss += __shfl_xor(ss, off);
        float rstd = rsqrtf(ss * 0.0078125f + 1e-5f);
        xs[row][lane]      = d0 * rstd * g0 + b0;
        xs[row][lane + 64] = d1 * rstd * g1 + b1;
    }
    __syncthreads();
    // vectorized bf16 store of x
    #pragma unroll
    for (int pass = 0; pass < 8; ++pass) {
        int idx = pass * 256 + tid;
        int r = idx >> 5, c = (idx & 31) * 4;
        ushort4 o;
        o.x = f2bf(xs[r][c + 0]); o.y = f2bf(xs[r][c + 1]);
        o.z = f2bf(xs[r][c + 2]); o.w = f2bf(xs[r][c + 3]);
        *reinterpret_cast<ushort4*>(&Xb[(size_t)(p0 + r) * DD + c]) = o;
    }
    // bias = x @ Wb, layout Bo[h][p]
    {
        const int r = tid >> 2, hh = tid & 3;
        float acc = 0.f;
        for (int e = 0; e < DD; ++e) acc += xs[r][e] * Wb[e * 4 + hh];
        Bo[(size_t)hh * 65536 + p0 + r] = f2bf(acc);
    }
}

// ---------------- K2: x @ [Wqkv|Wg] via MFMA, sigmoid on g -----------------
// grid (1024, 4): 64-row M-tile, 128-col N-tile. 256 thr = 4 waves (2x2).
__global__ __launch_bounds__(256) void k_gemm_qkvg(
    const ushort* __restrict__ Xb, const ushort* __restrict__ WT,
    const float* __restrict__ bg,
    ushort* __restrict__ Qo, ushort* __restrict__ Ko,
    ushort* __restrict__ Vo, ushort* __restrict__ Go)
{
    __shared__ __align__(16) ushort As[64][136];
    __shared__ __align__(16) ushort Bs[128][136];
    const int tid = threadIdx.x;
    const int p0 = blockIdx.x * 64, n0 = blockIdx.y * 128;
    #pragma unroll
    for (int it = 0; it < 4; ++it) {
        int idx = it * 256 + tid;
        int r = idx >> 4, c = (idx & 15) * 8;
        *reinterpret_cast<uint4*>(&As[r][c]) =
            *reinterpret_cast<const uint4*>(&Xb[(size_t)(p0 + r) * DD + c]);
    }
    #pragma unroll
    for (int it = 0; it < 8; ++it) {
        int idx = it * 256 + tid;
        int r = idx >> 4, c = (idx & 15) * 8;
        *reinterpret_cast<uint4*>(&Bs[r][c]) =
            *reinterpret_cast<const uint4*>(&WT[(size_t)(n0 + r) * DD + c]);
    }
    __syncthreads();
    const int w = tid >> 6, lane = tid & 63;
    const int wm = w >> 1, wn = w & 1;
    const int lr = lane & 15, lg = lane >> 4;
    const f32x4 zz = {0.f, 0.f, 0.f, 0.f};
    f32x4 acc[2][4];
    #pragma unroll
    for (int m = 0; m < 2; ++m)
        #pragma unroll
        for (int n = 0; n < 4; ++n) acc[m][n] = zz;
    #pragma unroll
    for (int kk = 0; kk < 4; ++kk) {
        bf16x8 a0 = *reinterpret_cast<const bf16x8*>(&As[wm * 32 + lr][kk * 32 + lg * 8]);
        bf16x8 a1 = *reinterpret_cast<const bf16x8*>(&As[wm * 32 + 16 + lr][kk * 32 + lg * 8]);
        #pragma unroll
        for (int n = 0; n < 4; ++n) {
            bf16x8 b = *reinterpret_cast<const bf16x8*>(&Bs[wn * 64 + n * 16 + lr][kk * 32 + lg * 8]);
            acc[0][n] = mfma16(a0, b, acc[0][n]);
            acc[1][n] = mfma16(a1, b, acc[1][n]);
        }
    }
    const int seg = n0 >> 7;   // 0:q 1:k 2:v 3:g (N-tile aligned to segment)
    #pragma unroll
    for (int n = 0; n < 4; ++n) {
        const int cc = (n0 & 127) + wn * 64 + n * 16 + lr;  // col within segment
        const float bgv = (seg == 3) ? bg[cc] : 0.f;
        #pragma unroll
        for (int m = 0; m < 2; ++m) {
            #pragma unroll
            for (int r = 0; r < 4; ++r) {
                const int p = p0 + wm * 32 + m * 16 + lg * 4 + r;
                const float v = acc[m][n][r];
                const size_t off = (size_t)p * DD + cc;
                if (seg == 0)      Qo[off] = f2bf(v);
                else if (seg == 1) Ko[off] = f2bf(v);
                else if (seg == 2) Vo[off] = f2bf(v);
                else Go[off] = f2bf(1.0f / (1.0f + __expf(-(v + bgv))));
            }
        }
    }
}

// ---------------- K3: attention per (i,h) with MFMA QK^T and PV ------------
__global__ __launch_bounds__(256) void k_attn2(
    const ushort* __restrict__ Qw, const ushort* __restrict__ Kw,
    const ushort* __restrict__ Vw, const ushort* __restrict__ Gw,
    const ushort* __restrict__ Bo, const int* __restrict__ mask,
    ushort* __restrict__ OPre)
{
    __shared__ __align__(16) ushort Ks[256][40];    // K rows, padded -> 2-way
    __shared__ __align__(16) ushort Vt[32][264];    // V^T, padded -> 2-way
    __shared__ __align__(16) ushort Qs[64][40];
    __shared__ __align__(16) ushort Pl[4][16][264]; // per-wave P tile
    const int tid = threadIdx.x, w = tid >> 6, lane = tid & 63;
    const int lr = lane & 15, lg = lane >> 4;
    const int i = blockIdx.x >> 2, h = blockIdx.x & 3;
    const int ib = i * NP;
    const size_t base = (size_t)i * NP * DD + h * 32;
    #pragma unroll
    for (int it = 0; it < 4; ++it) {
        int idx = it * 256 + tid;
        int r = idx >> 2, c = (idx & 3) * 8;
        *reinterpret_cast<uint4*>(&Ks[r][c]) =
            *reinterpret_cast<const uint4*>(&Kw[base + (size_t)r * DD + c]);
    }
    #pragma unroll
    for (int it = 0; it < 8; ++it) {
        int idx = it * 256 + tid;
        int k = idx >> 3, dc = (idx & 7) * 4;
        ushort4 v = *reinterpret_cast<const ushort4*>(&Vw[base + (size_t)k * DD + dc]);
        Vt[dc + 0][k] = v.x; Vt[dc + 1][k] = v.y;
        Vt[dc + 2][k] = v.z; Vt[dc + 3][k] = v.w;
    }
    const f32x4 zz = {0.f, 0.f, 0.f, 0.f};
    for (int jt = 0; jt < 4; ++jt) {
        const int j0 = jt * 64;
        {   // stage Q tile (safe: no other wave reads Qs between barriers)
            int r = tid >> 2, c = (tid & 3) * 8;
            *reinterpret_cast<uint4*>(&Qs[r][c]) =
                *reinterpret_cast<const uint4*>(&Qw[base + (size_t)(j0 + r) * DD + c]);
        }
        __syncthreads();
        // QK^T: wave w owns rows j0 + w*16 .. +15, all 256 keys
        f32x4 s[16];
        #pragma unroll
        for (int fn = 0; fn < 16; ++fn) s[fn] = zz;
        {
            bf16x8 a = *reinterpret_cast<const bf16x8*>(&Qs[w * 16 + lr][lg * 8]);
            #pragma unroll
            for (int fn = 0; fn < 16; ++fn) {
                bf16x8 b = *reinterpret_cast<const bf16x8*>(&Ks[fn * 16 + lr][lg * 8]);
                s[fn] = mfma16(a, b, s[fn]);
            }
        }
        const int jw = j0 + w * 16;
        int mbits = 0;
        #pragma unroll
        for (int r = 0; r < 4; ++r) {
            const int j = jw + lg * 4 + r;
            const bool masked = (mask[ib + j] == 0);
            if (masked) mbits |= (1 << r);
            const ushort* bp = Bo + (size_t)h * 65536 + (size_t)j * NP;
            float sv[16];
            float mx = -3.402823466e38f;
            #pragma unroll
            for (int fn = 0; fn < 16; ++fn) {
                sv[fn] = s[fn][r] * 0.17677669529663687f + bf2f(bp[fn * 16 + lr]);
                mx = fmaxf(mx, sv[fn]);
            }
            #pragma unroll
            for (int off2 = 1; off2 < 16; off2 <<= 1) mx = fmaxf(mx, __shfl_xor(mx, off2));
            float sum = 0.f;
            #pragma unroll
            for (int fn = 0; fn < 16; ++fn) { sv[fn] = __expf(sv[fn] - mx); sum += sv[fn]; }
            #pragma unroll
            for (int off2 = 1; off2 < 16; off2 <<= 1) sum += __shfl_xor(sum, off2);
            const float inv = 1.0f / sum;
            #pragma unroll
            for (int fn = 0; fn < 16; ++fn) {
                const float pv = masked ? 0.00390625f : sv[fn] * inv;  // 1/256 exact
                Pl[w][lg * 4 + r][fn * 16 + lr] = f2bf(pv);
            }
        }
        __syncthreads();
        // PV: O[16 rows][32 d] = P[16][256] @ V[256][32]
        f32x4 o0 = zz, o1 = zz;
        #pragma unroll
        for (int ks = 0; ks < 8; ++ks) {
            bf16x8 pa = *reinterpret_cast<const bf16x8*>(&Pl[w][lr][ks * 32 + lg * 8]);
            bf16x8 v0 = *reinterpret_cast<const bf16x8*>(&Vt[lr][ks * 32 + lg * 8]);
            bf16x8 v1 = *reinterpret_cast<const bf16x8*>(&Vt[16 + lr][ks * 32 + lg * 8]);
            o0 = mfma16(pa, v0, o0);
            o1 = mfma16(pa, v1, o1);
        }
        #pragma unroll
        for (int r = 0; r < 4; ++r) {
            const int j = jw + lg * 4 + r;
            const bool masked = (mbits >> r) & 1;
            const size_t off = base + (size_t)j * DD;
            const float g0 = masked ? NEGV : bf2f(Gw[off + lr]);
            const float g1 = masked ? NEGV : bf2f(Gw[off + 16 + lr]);
            OPre[off + lr]      = f2bf(o0[r] * g0);
            OPre[off + 16 + lr] = f2bf(o1[r] * g1);
        }
    }
}

// ---------------- K4: out = OPre @ Wout + bout (MFMA) ----------------------
__global__ __launch_bounds__(256) void k_gemm_out(
    const ushort* __restrict__ OPre, const ushort* __restrict__ WoT,
    const float* __restrict__ bout, float* __restrict__ out)
{
    __shared__ __align__(16) ushort As[64][136];
    __shared__ __align__(16) ushort Bs[128][136];
    const int tid = threadIdx.x;
    const int p0 = blockIdx.x * 64;
    #pragma unroll
    for (int it = 0; it < 4; ++it) {
        int idx = it * 256 + tid;
        int r = idx >> 4, c = (idx & 15) * 8;
        *reinterpret_cast<uint4*>(&As[r][c]) =
            *reinterpret_cast<const uint4*>(&OPre[(size_t)(p0 + r) * DD + c]);
    }
    #pragma unroll
    for (int it = 0; it < 8; ++it) {
        int idx = it * 256 + tid;
        int r = idx >> 4, c = (idx & 15) * 8;
        *reinterpret_cast<uint4*>(&Bs[r][c]) =
            *reinterpret_cast<const uint4*>(&WoT[(size_t)r * DD + c]);
    }
    __syncthreads();
    const int w = tid >> 6, lane = tid & 63;
    const int wm = w >> 1, wn = w & 1;
    const int lr = lane & 15, lg = lane >> 4;
    const f32x4 zz = {0.f, 0.f, 0.f, 0.f};
    f32x4 acc[2][4];
    #pragma unroll
    for (int m = 0; m < 2; ++m)
        #pragma unroll
        for (int n = 0; n < 4; ++n) acc[m][n] = zz;
    #pragma unroll
    for (int kk = 0; kk < 4; ++kk) {
        bf16x8 a0 = *reinterpret_cast<const bf16x8*>(&As[wm * 32 + lr][kk * 32 + lg * 8]);
        bf16x8 a1 = *reinterpret_cast<const bf16x8*>(&As[wm * 32 + 16 + lr][kk * 32 + lg * 8]);
        #pragma unroll
        for (int n = 0; n < 4; ++n) {
            bf16x8 b = *reinterpret_cast<const bf16x8*>(&Bs[wn * 64 + n * 16 + lr][kk * 32 + lg * 8]);
            acc[0][n] = mfma16(a0, b, acc[0][n]);
            acc[1][n] = mfma16(a1, b, acc[1][n]);
        }
    }
    #pragma unroll
    for (int n = 0; n < 4; ++n) {
        const int c = wn * 64 + n * 16 + lr;
        const float bo = bout[c];
        #pragma unroll
        for (int m = 0; m < 2; ++m) {
            #pragma unroll
            for (int r = 0; r < 4; ++r) {
                const int p = p0 + wm * 32 + m * 16 + lg * 4 + r;
                out[(size_t)p * DD + c] = acc[m][n][r] + bo;
            }
        }
    }
}

extern "C" void kernel_launch(void* const* d_in, const int* in_sizes, int n_in,
                              void* d_out, int out_size, void* d_ws, size_t ws_size,
                              hipStream_t stream) {
    const float* edges = (const float*)d_in[0];
    const int*   mask  = (const int*)d_in[1];
    const float* gamma = (const float*)d_in[2];
    const float* beta  = (const float*)d_in[3];
    const float* Wqkv  = (const float*)d_in[4];
    const float* Wb    = (const float*)d_in[5];
    const float* Wg    = (const float*)d_in[6];
    const float* bg    = (const float*)d_in[7];
    const float* Wout  = (const float*)d_in[8];
    const float* bout  = (const float*)d_in[9];
    float* out = (float*)d_out;

    char* ws = (char*)d_ws;
    // 16 MiB each; OPre aliases Xb (Xb dead after k_gemm_qkvg).
    ushort* Xb  = (ushort*)(ws);
    ushort* Qw  = (ushort*)(ws + 1u * 16777216u);
    ushort* Kw  = (ushort*)(ws + 2u * 16777216u);
    ushort* Vw  = (ushort*)(ws + 3u * 16777216u);
    ushort* Gw  = (ushort*)(ws + 4u * 16777216u);
    ushort* Bo  = (ushort*)(ws + 5u * 16777216u);             // 512 KiB
    ushort* WT  = (ushort*)(ws + 5u * 16777216u + 524288u);   // 128 KiB
    ushort* WoT = (ushort*)(ws + 5u * 16777216u + 524288u + 131072u); // 32 KiB
    ushort* OPre = Xb;
    // total 84,574,208 B (<= round-0 footprint)

    k_wconv<<<dim3(320), dim3(256), 0, stream>>>(Wqkv, Wg, Wout, WT, WoT);
    k_ln<<<dim3(1024), dim3(256), 0, stream>>>(edges, gamma, beta, Wb, Xb, Bo);
    k_gemm_qkvg<<<dim3(1024, 4), dim3(256), 0, stream>>>(Xb, WT, bg, Qw, Kw, Vw, Gw);
    k_attn2<<<dim3(1024), dim3(256), 0, stream>>>(Qw, Kw, Vw, Gw, Bo, mask, OPre);
    k_gemm_out<<<dim3(1024), dim3(256), 0, stream>>>(OPre, WoT, bout, out);
}